// Round 1
// 168.488 us; speedup vs baseline: 1.0809x; 1.0809x over previous
//
#include <hip/hip_runtime.h>

// Problem constants (from reference setup_inputs)
#define BATCH 16
#define NCLS 19
#define HW (1024 * 2048)            // elements per batch image
#define BLOCKS_PER_BATCH 128
#define THREADS 256
#define VEC_PER_BLOCK (HW / 4 / BLOCKS_PER_BATCH)   // 4096 int4 per block
#define ITERS (VEC_PER_BLOCK / THREADS)             // 16 int4 per thread
#define FULLMASK ((1u << NCLS) - 1)                 // 0x7FFFF: all 19 classes seen

typedef int iv4 __attribute__((ext_vector_type(4)));  // clang vector: OK for nontemporal builtin

// Kernel 1: per-block class-presence bitmask over a contiguous chunk of targets.
// 2048 blocks x 256 thr. EARLY-EXIT DESIGN: the OR-mask saturates — once a wave
// has seen all 19 classes (mask == 0x7FFFF) in its first int4/lane (256 values),
// no further load can change the block's output, so skipping the remaining 15
// int4/lane is EXACT for any input. For uniform-random targets the slow path
// fires with prob ~2e-5 per wave -> steady-state reads drop 134 MB -> ~8.4 MB.
// Adversarial inputs (some class absent) fall through to the full read.
__global__ __launch_bounds__(THREADS)
void presence_kernel(const int* __restrict__ targets, unsigned* __restrict__ partial) {
    const int b   = blockIdx.x >> 7;          // / BLOCKS_PER_BATCH
    const int blk = blockIdx.x & (BLOCKS_PER_BATCH - 1);

    const iv4* tv = (const iv4*)targets
                  + (long long)b * (HW / 4)
                  + (long long)blk * VEC_PER_BLOCK
                  + threadIdx.x;

    __shared__ unsigned sm[THREADS / 64];
    const int lane = threadIdx.x & 63;
    const int wave = threadIdx.x >> 6;

    // Fast path: one int4 per lane (4 KB per block), wave-wide OR.
    iv4 v0 = __builtin_nontemporal_load(&tv[0]);
    unsigned m = (1u << v0.x) | (1u << v0.y) | (1u << v0.z) | (1u << v0.w);

    unsigned r = m;
    #pragma unroll
    for (int off = 32; off; off >>= 1) r |= __shfl_xor(r, off);  // butterfly: all lanes hold full OR

    if ((r & FULLMASK) != FULLMASK) {
        // Slow path (prob ~2e-5 per wave on this input; correctness fallback).
        // Kept rolled to avoid burning 60 VGPRs on a never-taken path.
        #pragma unroll 1
        for (int i = 1; i < ITERS; i++) {
            iv4 t = __builtin_nontemporal_load(&tv[i * THREADS]);
            m |= (1u << t.x) | (1u << t.y) | (1u << t.z) | (1u << t.w);
        }
        #pragma unroll
        for (int off = 32; off; off >>= 1) m |= __shfl_xor(m, off);
        r = m;
    }

    if (lane == 0) sm[wave] = r;
    __syncthreads();
    if (threadIdx.x == 0)
        partial[blockIdx.x] = sm[0] | sm[1] | sm[2] | sm[3];  // unconditional write
}

// Kernel 2: single block. OR-reduce 2048 partials -> 16 presence masks, then
// stable BCE-with-logits over the 304 logits, mean, write scalar.
__global__ __launch_bounds__(512)
void loss_kernel(const float* __restrict__ preds, const unsigned* __restrict__ partial,
                 float* __restrict__ out) {
    __shared__ unsigned bm[BATCH];
    __shared__ float red[8];

    const int tid = threadIdx.x;  // 512 threads

    // Reduce 2048 partials: 32 threads per batch, 4 loads each.
    {
        const int b = tid >> 5;       // 0..15
        const int j = tid & 31;
        unsigned m = 0;
        #pragma unroll
        for (int k = 0; k < BLOCKS_PER_BATCH / 32; k++)
            m |= partial[b * BLOCKS_PER_BATCH + j + 32 * k];
        #pragma unroll
        for (int off = 16; off; off >>= 1) m |= __shfl_down(m, off, 32);
        if (j == 0) bm[b] = m;
    }
    __syncthreads();

    float v = 0.0f;
    if (tid < BATCH * NCLS) {
        const int b = tid / NCLS;
        const int c = tid % NCLS;
        const float x = preds[tid];
        const float t = ((bm[b] >> c) & 1u) ? 1.0f : 0.0f;
        // BCE with logits, numerically stable:
        // -(t*logsig(x) + (1-t)*logsig(-x)) = max(x,0) - x*t + log1p(exp(-|x|))
        v = fmaxf(x, 0.0f) - x * t + log1pf(expf(-fabsf(x)));
    }

    // wave-64 sum reduction
    #pragma unroll
    for (int off = 32; off; off >>= 1) v += __shfl_down(v, off);

    const int lane = tid & 63;
    const int wave = tid >> 6;
    if (lane == 0) red[wave] = v;
    __syncthreads();
    if (tid == 0) {
        float s = 0.0f;
        #pragma unroll
        for (int w = 0; w < 8; w++) s += red[w];
        out[0] = s * (1.0f / (float)(BATCH * NCLS));
    }
}

extern "C" void kernel_launch(void* const* d_in, const int* in_sizes, int n_in,
                              void* d_out, int out_size, void* d_ws, size_t ws_size,
                              hipStream_t stream) {
    const float* preds   = (const float*)d_in[0];   // [16, 19] fp32 logits
    const int*   targets = (const int*)d_in[1];     // [16, 1024, 2048] int32
    unsigned*    partial = (unsigned*)d_ws;         // 2048 uints = 8 KB
    float*       out     = (float*)d_out;           // scalar fp32

    presence_kernel<<<BATCH * BLOCKS_PER_BATCH, THREADS, 0, stream>>>(targets, partial);
    loss_kernel<<<1, 512, 0, stream>>>(preds, partial, out);
}